// Round 9
// baseline (474.438 us; speedup 1.0000x reference)
//
#include <hip/hip_runtime.h>

typedef _Float16 f16;
typedef __attribute__((ext_vector_type(8))) _Float16 half8;
typedef __attribute__((ext_vector_type(4))) _Float16 half4;
typedef __attribute__((ext_vector_type(4))) float floatx4;
typedef unsigned int uint32;
typedef __attribute__((ext_vector_type(4))) uint32 uint4v;

#define MFMA16(a, b, c) __builtin_amdgcn_mfma_f32_16x16x32_f16((a), (b), (c), 0, 0, 0)

constexpr int B_ = 4, M_ = 1024, N_ = 4096, DQ_ = 512, DC_ = 512, H_ = 8, DH_ = 64, D_ = 512;
constexpr int KP_ = 576;       // K row stride (halves)
constexpr int VP_ = 4224;      // Vt row stride (halves)
constexpr int NSPLIT = 4;      // proven L2-coherent split
constexpr float QSC_ = 0.18033688011112042f;  // 0.125 * log2(e)

typedef __attribute__((address_space(1))) const void glds_g;
typedef __attribute__((address_space(3))) void glds_l;
__device__ __forceinline__ void g2lds16(const void* g, void* l) {
    __builtin_amdgcn_global_load_lds((glds_g*)g, (glds_l*)l, 16, 0, 0);
}

// ---- 64x64 f32->f16 transpose tile through LDS (device helper) ----
__device__ __forceinline__ void wtr_tile(const float* __restrict__ src, f16* __restrict__ dst,
                                         int Nout, int bx, int by, int tid) {
    __shared__ __align__(16) f16 Ts[64][72];
    const int n0 = bx * 64, k0 = by * 64;
    {
        int kr = tid >> 2, q4 = tid & 3;
        const float* sp = src + (size_t)(k0 + kr) * Nout + n0 + q4 * 16;
        float4 x0 = *(const float4*)(sp + 0), x1 = *(const float4*)(sp + 4);
        float4 x2 = *(const float4*)(sp + 8), x3 = *(const float4*)(sp + 12);
        half8 h0, h1;
        h0[0]=(f16)x0.x; h0[1]=(f16)x0.y; h0[2]=(f16)x0.z; h0[3]=(f16)x0.w;
        h0[4]=(f16)x1.x; h0[5]=(f16)x1.y; h0[6]=(f16)x1.z; h0[7]=(f16)x1.w;
        h1[0]=(f16)x2.x; h1[1]=(f16)x2.y; h1[2]=(f16)x2.z; h1[3]=(f16)x2.w;
        h1[4]=(f16)x3.x; h1[5]=(f16)x3.y; h1[6]=(f16)x3.z; h1[7]=(f16)x3.w;
        *(half8*)&Ts[kr][q4 * 16] = h0;
        *(half8*)&Ts[kr][q4 * 16 + 8] = h1;
    }
    __syncthreads();
    {
        int nr = tid >> 2, q = tid & 3;
        half8 h0, h1;
#pragma unroll
        for (int j = 0; j < 8; j++) { h0[j] = Ts[q * 16 + j][nr]; h1[j] = Ts[q * 16 + 8 + j][nr]; }
        f16* dp = dst + (size_t)(n0 + nr) * 512 + k0 + q * 16;
        *(half8*)(dp + 0) = h0;
        *(half8*)(dp + 8) = h1;
    }
}

// ---------------- prep: mask-pack + weight transposes only (casts fused into gemmqkv) --------
__global__ __launch_bounds__(256)
void prep_k(const void* __restrict__ mask, uint32* __restrict__ bits,
            const float* __restrict__ Wq, f16* __restrict__ wqt,
            const float* __restrict__ Wkv, f16* __restrict__ wkvt,
            const float* __restrict__ Wout, f16* __restrict__ woutt) {
    const int blk = blockIdx.x, tid = threadIdx.x;
    if (blk < 4096) {
        // dtype detect on the block's OWN 4KB word-window (in-bounds both layouts)
        __shared__ int s_bad;
        if (tid == 0) s_bad = 0;
        __syncthreads();
        const uint32* w = (const uint32*)mask + (size_t)blk * 1024;
        int bad = 0;
#pragma unroll
        for (int j = 0; j < 4; j++) bad |= (w[tid * 4 + j] & 0xFFFFFFFEu) != 0u;
        if (bad) s_bad = 1;  // benign race: all writers store 1
        __syncthreads();
        const bool bytes_mode = s_bad != 0;
        // thread owns elems [blk*4096 + tid*16, +16)
        uint32 v = 0;
        if (bytes_mode) {
            uint4 x = *(const uint4*)((const unsigned char*)mask + (size_t)blk * 4096 + tid * 16);
            uint32 ws_[4] = {x.x, x.y, x.z, x.w};
#pragma unroll
            for (int k = 0; k < 4; k++)
#pragma unroll
                for (int bb = 0; bb < 4; bb++)
                    v |= (((ws_[k] >> (8 * bb)) & 0xFFu) != 0u ? 1u : 0u) << (k * 4 + bb);
        } else {
            const uint4* p = (const uint4*)((const uint32*)mask + (size_t)blk * 4096 + tid * 16);
            uint4 x0 = p[0], x1 = p[1], x2 = p[2], x3 = p[3];
            uint32 ws_[16] = {x0.x, x0.y, x0.z, x0.w, x1.x, x1.y, x1.z, x1.w,
                              x2.x, x2.y, x2.z, x2.w, x3.x, x3.y, x3.z, x3.w};
#pragma unroll
            for (int k = 0; k < 16; k++) v |= (ws_[k] != 0u ? 1u : 0u) << k;
        }
        uint32 other = (uint32)__shfl_xor((int)v, 1);
        if ((tid & 1) == 0)
            bits[(size_t)blk * 128 + (tid >> 1)] = v | (other << 16);
    } else if (blk < 4160) {
        int r = blk - 4096;
        wtr_tile(Wq, wqt, 512, r & 7, r >> 3, tid);
    } else if (blk < 4288) {
        int r = blk - 4160;
        wtr_tile(Wkv, wkvt, 1024, r & 15, r >> 4, tid);
    } else {
        int r = blk - 4288;
        wtr_tile(Wout, woutt, 512, r & 7, r >> 3, tid);
    }
}

// ---------------- fused cast + q/kv-proj GEMM v2: 256x128 tile, 512 threads ------------------
// Round-8 version held ra[4][2] (32 VGPR) across the MFMA phase on top of a 64-reg acc ->
// ~145 live regs, likely scratch-spilling (the same silent failure mode attn hit twice).
// v2: transient staging (f32 load -> cvt -> immediate ds_write, nothing held across compute),
// 256x128 tile halves staging bytes + barriers per output, launch_bounds(512,4) caps at 128
// VGPR (peak live ~115). V-half handled by FLIPPING MFMA operand order (mfma(wf,rf)) instead
// of swapping tiles: every wave's LDS reads are identical across modes; coalesced vt scatter
// preserved. XCD decode: W-panels cycle fast (1MB resident), each R-panel fetched once/XCD.
__global__ __launch_bounds__(512, 4)
void gemmqkv_k(const float* __restrict__ left, const f16* __restrict__ wqt,
               const float* __restrict__ right, const f16* __restrict__ wkvt,
               f16* __restrict__ qb, f16* __restrict__ kb, f16* __restrict__ vt) {
    __shared__ __align__(16) f16 Rs[256 * 64];   // f32-source operand (right/left), 32KB
    __shared__ __align__(16) f16 Ws[128 * 64];   // f16 weight operand, 16KB
    const int hw = blockIdx.x, tid = threadIdx.x;
    const int lane = tid & 63, wave = tid >> 6;  // 8 waves
    const int qd = lane >> 4, l16 = lane & 15;
    const int wr = wave >> 1;   // R-side 64-block 0..3
    const int ww = wave & 1;    // W-side 64-block 0..1

    // mode: 0 = K-half kv, 1 = V-half kv (operand-flipped), 2 = q
    int mode; size_t rbase, wbase;
    const float* Rg; const f16* Wg;
    if (hw < 512) {
        const int xcd = hw & 7, s = hw >> 3;        // s 0..63
        const int wpan = s & 7, rpan = xcd * 8 + (s >> 3);
        rbase = (size_t)rpan * 256; wbase = (size_t)wpan * 128;
        Rg = right; Wg = wkvt;
        mode = (wpan < 4) ? 0 : 1;
    } else {
        const int r = hw - 512;
        const int xcd = r & 7, s = r >> 3;          // s 0..7
        const int wpan = s & 3, rpan = xcd * 2 + (s >> 2);
        rbase = (size_t)rpan * 256; wbase = (size_t)wpan * 128;
        Rg = left; Wg = wqt;
        mode = 2;
    }
    const float* Rb = Rg + rbase * 512;
    const f16*  Wb = Wg + wbase * 512;

    // W staging (g2lds): 1024 chunks, 2/thread; pre-swizzled global source, linear LDS dest
    size_t wgoff[2]; f16* wdst[2];
#pragma unroll
    for (int i = 0; i < 2; i++) {
        int c = i * 512 + tid;
        int row = c >> 3, col8 = (c & 7) ^ (row & 7);
        wgoff[i] = (size_t)row * 512 + col8 * 8;
        wdst[i] = Ws + (size_t)(i * 512 + wave * 64) * 8;
    }
    // R staging geometry: 2048 chunks, 4/thread (transient regs only)
    int rrow[4], rcol8[4];
#pragma unroll
    for (int i = 0; i < 4; i++) {
        int c = i * 512 + tid;
        rrow[i] = c >> 3; rcol8[i] = (c & 7) ^ (rrow[i] & 7);
    }

    floatx4 acc[4][4] = {};

    for (int k0 = 0; k0 < 512; k0 += 64) {
        __syncthreads();
#pragma unroll
        for (int i = 0; i < 2; i++) g2lds16(Wb + wgoff[i] + k0, wdst[i]);
#pragma unroll
        for (int i = 0; i < 4; i++) {
            const float* sp = Rb + (size_t)rrow[i] * 512 + k0 + rcol8[i] * 8;
            float4 x0 = *(const float4*)sp, x1 = *(const float4*)(sp + 4);
            half8 hh;
            hh[0]=(f16)x0.x; hh[1]=(f16)x0.y; hh[2]=(f16)x0.z; hh[3]=(f16)x0.w;
            hh[4]=(f16)x1.x; hh[5]=(f16)x1.y; hh[6]=(f16)x1.z; hh[7]=(f16)x1.w;
            *(half8*)&Rs[(size_t)(i * 512 + tid) * 8] = hh;
        }
        __syncthreads();
#pragma unroll
        for (int kk = 0; kk < 2; kk++) {
            half8 rf[4], wf[4];
#pragma unroll
            for (int t = 0; t < 4; t++) {
                int rowr = wr * 64 + t * 16 + l16;
                int roww = ww * 64 + t * 16 + l16;
                rf[t] = *(const half8*)&Rs[rowr * 64 + (((kk * 4 + qd) ^ (rowr & 7)) * 8)];
                wf[t] = *(const half8*)&Ws[roww * 64 + (((kk * 4 + qd) ^ (roww & 7)) * 8)];
            }
            if (mode == 1) {
#pragma unroll
                for (int mt = 0; mt < 4; mt++)
#pragma unroll
                    for (int nt = 0; nt < 4; nt++)
                        acc[mt][nt] = MFMA16(wf[mt], rf[nt], acc[mt][nt]);
            } else {
#pragma unroll
                for (int mt = 0; mt < 4; mt++)
#pragma unroll
                    for (int nt = 0; nt < 4; nt++)
                        acc[mt][nt] = MFMA16(rf[mt], wf[nt], acc[mt][nt]);
            }
        }
    }

    if (mode == 1) {
        // C rows = W-cols (dcol), C cols = R-rows (n-index); coalesced vt scatter (nn = l16)
#pragma unroll
        for (int mt = 0; mt < 4; mt++)
#pragma unroll
            for (int nt = 0; nt < 4; nt++)
#pragma unroll
                for (int r = 0; r < 4; r++) {
                    int dcol = (int)wbase + ww * 64 + mt * 16 + qd * 4 + r - 512;
                    size_t ni = rbase + wr * 64 + nt * 16 + l16;
                    int hh2 = dcol >> 6, dh = dcol & 63;
                    size_t bb = ni >> 12, nn = ni & 4095;
                    vt[((bb * H_ + hh2) * (size_t)DH_ + dh) * VP_ + nn] = (f16)acc[mt][nt][r];
                }
    } else {
#pragma unroll
        for (int mt = 0; mt < 4; mt++)
#pragma unroll
            for (int nt = 0; nt < 4; nt++)
#pragma unroll
                for (int r = 0; r < 4; r++) {
                    size_t mi = rbase + wr * 64 + mt * 16 + qd * 4 + r;
                    size_t ni = wbase + ww * 64 + nt * 16 + l16;
                    if (mode == 2) qb[mi * 512 + ni] = (f16)acc[mt][nt][r];
                    else           kb[mi * KP_ + ni] = (f16)acc[mt][nt][r];
                }
    }
}

// ---------------- flash attention v4 (proven 66us): 8 thin waves, dbuf staging ---------------
__global__ __launch_bounds__(512, 8)
void attn_k(const f16* __restrict__ Qb, const f16* __restrict__ Kb,
            const f16* __restrict__ Vt, const uint32* __restrict__ mb,
            float* __restrict__ Op, float* __restrict__ Lp) {
    const int tid = threadIdx.x;
    const int lane = tid & 63, wave = tid >> 6;     // wave 0..7
    const int qd = lane >> 4, l16 = lane & 15;
    const int bh = blockIdx.x, b = bh >> 3, h = bh & 7;
    const int z = blockIdx.z;
    constexpr int iters = N_ / (64 * NSPLIT);   // 16
    const int n_base = z * iters * 64;
    const int m_base = blockIdx.y * 128 + wave * 16;

    __shared__ __align__(16) f16 Ks[2][64 * 64];   // [n][d] chunks, xor-swizzled
    __shared__ __align__(16) f16 Vs[2][64 * 64];   // [dh][n] chunks, xor-swizzled

    // Q B-operand fragments for this wave's 16 rows, pre-scaled by 0.125*log2(e)
    half8 q0, q1;
    {
        const f16* qrow = Qb + ((size_t)(b * M_ + m_base + l16)) * D_ + h * DH_;
        half8 r0 = *(const half8*)(qrow + qd * 8);
        half8 r1 = *(const half8*)(qrow + 32 + qd * 8);
#pragma unroll
        for (int j = 0; j < 8; j++) {
            q0[j] = (f16)((float)r0[j] * QSC_);
            q1[j] = (f16)((float)r1[j] * QSC_);
        }
    }

    floatx4 ot[4] = {};   // O^T: ot[sd][r] = O[m=l16][d = sd*16+qd*4+r]
    float l_acc = 0.0f;   // partial softmax denom for m=l16 over this lane's n subset

    // mask row for m = l16
    const uint32* mrow = mb + ((size_t)(b * M_ + m_base + l16)) * (N_ / 32);

    // staging: wave w owns 8 rows [8w, 8w+8) of each tile, 1 g2lds16 each for K and V.
    const int srow = wave * 8;
    const int r8 = lane >> 3, p8 = lane & 7;
    const int gc8 = p8 ^ r8;
    const f16* kg = Kb + ((size_t)(b * N_) + srow + r8) * KP_ + h * DH_ + gc8 * 8;
    const f16* vg = Vt + ((size_t)(bh * DH_) + srow + r8) * VP_ + gc8 * 8;

    auto stage = [&](int buf, int n0) {
        g2lds16(kg + (size_t)n0 * KP_, &Ks[buf][srow * 64]);
        g2lds16(vg + n0, &Vs[buf][srow * 64]);
    };

    stage(0, n_base);
    uint2 mmc = *(const uint2*)(mrow + (n_base >> 5));
    int cur = 0;

    const int swz = (l16 & 7);   // read-side xor base

    for (int it = 0; it < iters; it++) {
        const int n0 = n_base + it * 64;
        __syncthreads();
        uint2 mmn;
        if (it + 1 < iters) {
            stage(cur ^ 1, n0 + 64);
            mmn = *(const uint2*)(mrow + ((n0 + 64) >> 5));
        }

        const uint32 u0 = mmc.x >> (qd * 4);
        const uint32 u1 = mmc.y >> (qd * 4);

        // S^T = K·Q^T per 16-n subtile; mask; P = exp2; accumulate l; pack pairs (RTZ)
        uint32 pk[4][2];
#pragma unroll
        for (int s = 0; s < 4; s++) {
            const int ro = (s * 16 + l16) * 64;
            half8 k0 = *(const half8*)&Ks[cur][ro + ((qd ^ swz) * 8)];
            half8 k1 = *(const half8*)&Ks[cur][ro + (((4 + qd) ^ swz) * 8)];
            floatx4 t = {};
            t = MFMA16(k0, q0, t);
            t = MFMA16(k1, q1, t);
            uint32 us = (s & 2 ? u1 : u0) >> ((s & 1) * 16);
            float e0 = __builtin_amdgcn_exp2f(t[0]);
            float e1 = __builtin_amdgcn_exp2f(t[1]);
            float e2 = __builtin_amdgcn_exp2f(t[2]);
            float e3 = __builtin_amdgcn_exp2f(t[3]);
            e0 = (us & 1u) ? e0 : 0.0f;
            e1 = (us & 2u) ? e1 : 0.0f;
            e2 = (us & 4u) ? e2 : 0.0f;
            e3 = (us & 8u) ? e3 : 0.0f;
            l_acc += (e0 + e1) + (e2 + e3);
            pk[s][0] = __builtin_bit_cast(uint32, __builtin_amdgcn_cvt_pkrtz(e0, e1));
            pk[s][1] = __builtin_bit_cast(uint32, __builtin_amdgcn_cvt_pkrtz(e2, e3));
        }

        // In-register routing: pa[hh] lane(qd,l16) elem j = P[m=l16][n=32hh+8qd+j]
        half8 pa[2];
#pragma unroll
        for (int hh = 0; hh < 2; hh++) {
            uint32 w0, w1, w2, w3;
            {
                auto a = __builtin_amdgcn_permlane32_swap(pk[2 * hh][0], pk[2 * hh + 1][0], false, false);
                auto c = __builtin_amdgcn_permlane16_swap(a[0], a[1], false, false);
                w0 = c[0]; w2 = c[1];
            }
            {
                auto a = __builtin_amdgcn_permlane32_swap(pk[2 * hh][1], pk[2 * hh + 1][1], false, false);
                auto c = __builtin_amdgcn_permlane16_swap(a[0], a[1], false, false);
                w1 = c[0]; w3 = c[1];
            }
            uint4v wv = {w0, w1, w2, w3};
            pa[hh] = __builtin_bit_cast(half8, wv);
        }

        // O^T += V^T @ P^T
#pragma unroll
        for (int sd = 0; sd < 4; sd++) {
            const int ro = (sd * 16 + l16) * 64;
            half8 v0 = *(const half8*)&Vs[cur][ro + ((qd ^ swz) * 8)];
            half8 v1 = *(const half8*)&Vs[cur][ro + (((4 + qd) ^ swz) * 8)];
            ot[sd] = MFMA16(v0, pa[0], ot[sd]);
            ot[sd] = MFMA16(v1, pa[1], ot[sd]);
        }
        mmc = mmn;
        cur ^= 1;
    }

    // reduce l over the 4 qd-lanes holding the same m (lane bits 4,5)
    l_acc += __shfl_xor(l_acc, 16);
    l_acc += __shfl_xor(l_acc, 32);

    // store f32 partials (non-temporal: don't evict K/V from L2)
    {
        size_t row = (size_t)(z * 32 + bh) * M_ + m_base + l16;
        float* op = Op + row * DH_ + qd * 4;
#pragma unroll
        for (int sd = 0; sd < 4; sd++)
            __builtin_nontemporal_store(ot[sd], (floatx4*)(op + sd * 16));
        if (qd == 0) __builtin_nontemporal_store(l_acc, Lp + row);
    }
}

// ---------------- combine splits: Ob = (sum Op) / (sum l), f16 (B*M, D), float4 ----------------
__global__ __launch_bounds__(256)
void comb_k(const float* __restrict__ Op, const float* __restrict__ Lp, f16* __restrict__ Ob,
            int nsp) {
    int i = blockIdx.x * 256 + threadIdx.x;   // B*M*D/4 = 524288 threads
    int d4 = i & 15, m = (i >> 4) & 1023, bh = i >> 14;
    float nx = 0.f, ny = 0.f, nz = 0.f, nw = 0.f, den = 0.f;
    for (int s = 0; s < nsp; s++) {
        size_t row = ((size_t)s * 32 + bh) * M_ + m;
        float4 x = *(const float4*)(Op + row * DH_ + d4 * 4);
        nx += x.x; ny += x.y; nz += x.z; nw += x.w;
        den += Lp[row];
    }
    float r = 1.0f / den;
    int b = bh >> 3, h = bh & 7;
    f16* o = Ob + ((size_t)(b * M_ + m)) * D_ + h * DH_ + d4 * 4;
    half4 hv; hv[0] = (f16)(nx * r); hv[1] = (f16)(ny * r); hv[2] = (f16)(nz * r); hv[3] = (f16)(nw * r);
    *(half4*)o = hv;
}

// ---------------- out-projection GEMM: 64x64 tiles, 2-phase double-buffered ----------------
__global__ __launch_bounds__(256)
void gemmout_k(const f16* __restrict__ A, const f16* __restrict__ Bt,
               float* __restrict__ Fout, const float* __restrict__ bias) {
    __shared__ __align__(16) f16 As[2][64 * 64];
    __shared__ __align__(16) f16 Bs[2][64 * 64];
    const int tid = threadIdx.x;
    const int lane = tid & 63, wave = tid >> 6;
    const int qd = lane >> 4, l16 = lane & 15;
    const int wm = wave >> 1, wn = wave & 1;
    const size_t m0 = (size_t)blockIdx.x * 64;
    const size_t n0 = (size_t)blockIdx.y * 64;

    size_t goff[2];
    f16 *la[2][2], *lb[2][2];
#pragma unroll
    for (int i = 0; i < 2; i++) {
        int c = i * 256 + wave * 64 + lane;
        int row = c >> 3, col8 = (c & 7) ^ (row & 7);
        goff[i] = (size_t)row * 512 + col8 * 8;
        la[0][i] = &As[0][(size_t)(i * 256 + wave * 64) * 8];
        la[1][i] = &As[1][(size_t)(i * 256 + wave * 64) * 8];
        lb[0][i] = &Bs[0][(size_t)(i * 256 + wave * 64) * 8];
        lb[1][i] = &Bs[1][(size_t)(i * 256 + wave * 64) * 8];
    }
    const f16* Ab = A + m0 * 512;
    const f16* Bb = Bt + n0 * 512;

    floatx4 acc[2][2] = {};

#pragma unroll
    for (int i = 0; i < 2; i++) g2lds16(Ab + goff[i], la[0][i]);
#pragma unroll
    for (int i = 0; i < 2; i++) g2lds16(Bb + goff[i], lb[0][i]);
    int cur = 0;

    for (int k0 = 0; k0 < 512; k0 += 64) {
        __syncthreads();
        if (k0 + 64 < 512) {
            const int nxt = cur ^ 1;
#pragma unroll
            for (int i = 0; i < 2; i++) g2lds16(Ab + goff[i] + k0 + 64, la[nxt][i]);
#pragma unroll
            for (int i = 0; i < 2; i++) g2lds16(Bb + goff[i] + k0 + 64, lb[nxt][i]);
        }
        const f16* Ac = &As[cur][0];
        const f16* Bc = &Bs[cur][0];
#pragma unroll
        for (int kk = 0; kk < 2; kk++) {
            half8 a[2], b[2];
#pragma unroll
            for (int t = 0; t < 2; t++) {
                int rowa = wm * 32 + t * 16 + l16;
                int rowb = wn * 32 + t * 16 + l16;
                int pa8 = ((kk * 4 + qd) ^ (rowa & 7)) * 8;
                int pb8 = ((kk * 4 + qd) ^ (rowb & 7)) * 8;
                a[t] = *(const half8*)&Ac[rowa * 64 + pa8];
                b[t] = *(const half8*)&Bc[rowb * 64 + pb8];
            }
#pragma unroll
            for (int mt = 0; mt < 2; mt++)
#pragma unroll
                for (int nt = 0; nt < 2; nt++)
                    acc[mt][nt] = MFMA16(a[mt], b[nt], acc[mt][nt]);
        }
        cur ^= 1;
    }

#pragma unroll
    for (int mt = 0; mt < 2; mt++)
#pragma unroll
        for (int nt = 0; nt < 2; nt++)
#pragma unroll
            for (int r = 0; r < 4; r++) {
                size_t row = m0 + wm * 32 + mt * 16 + qd * 4 + r;
                size_t col = n0 + wn * 32 + nt * 16 + l16;
                Fout[row * 512 + col] = acc[mt][nt][r] + bias[col];
            }
}

extern "C" void kernel_launch(void* const* d_in, const int* in_sizes, int n_in,
                              void* d_out, int out_size, void* d_ws, size_t ws_size,
                              hipStream_t stream) {
    const float* left  = (const float*)d_in[0];
    const float* right = (const float*)d_in[1];
    const void*  mask  = d_in[2];
    const float* Wq    = (const float*)d_in[3];
    const float* Wkv   = (const float*)d_in[4];
    const float* Wout  = (const float*)d_in[5];
    const float* bout  = (const float*)d_in[6];

    char* ws = (char*)d_ws;
    size_t off = 0;
    auto take = [&](size_t bytes) { char* p = ws + off; off += (bytes + 255) & ~(size_t)255; return p; };
    // ---- fixed allocations ----
    uint32* mbits = (uint32*)take((size_t)B_ * M_ * N_ / 8);           // 2 MB
    f16* woutt = (f16*)take((size_t)D_ * DQ_ * 2);                     // 0.5 MB
    f16* qb    = (f16*)take((size_t)B_ * M_ * D_ * 2);                 // 4 MB
    f16* kb    = (f16*)take((size_t)B_ * N_ * KP_ * 2);                // 18.9 MB (padded)
    f16* vt    = (f16*)take((size_t)B_ * H_ * DH_ * VP_ * 2);          // 17.3 MB (padded)
    f16* ob    = (f16*)take((size_t)B_ * M_ * D_ * 2);                 // 4 MB
    // ---- phase-overlay pool ----
    // phase 1 (prep+gemmqkv): wqt(0.5) wkvt(1)
    // phase 2 (attn+comb):    Op(32) + Lp(0.5) overlays the dead phase-1 buffers
    char* pool = (char*)take((size_t)34 * 1024 * 1024);
    f16* wqt    = (f16*)pool;
    f16* wkvt   = (f16*)(pool + (size_t)1 * 1024 * 1024);
    float* Op   = (float*)pool;                                        // 32 MB
    float* Lp   = (float*)(pool + (size_t)NSPLIT * 32 * M_ * DH_ * 4); // 0.5 MB

    // 5 dispatches total
    prep_k<<<4352, 256, 0, stream>>>(mask, mbits, Wq, wqt, Wkv, wkvt, Wout, woutt);
    gemmqkv_k<<<576, 512, 0, stream>>>(left, wqt, right, wkvt, qb, kb, vt);
    attn_k<<<dim3(32, 8, NSPLIT), 512, 0, stream>>>(qb, kb, vt, mbits, Op, Lp);
    comb_k<<<2048, 256, 0, stream>>>(Op, Lp, ob, NSPLIT);
    gemmout_k<<<dim3(64, 8), 256, 0, stream>>>(ob, woutt, (float*)d_out, bout);
}

// Round 10
// 350.348 us; speedup vs baseline: 1.3542x; 1.3542x over previous
//
#include <hip/hip_runtime.h>

typedef _Float16 f16;
typedef __attribute__((ext_vector_type(8))) _Float16 half8;
typedef __attribute__((ext_vector_type(4))) _Float16 half4;
typedef __attribute__((ext_vector_type(4))) float floatx4;
typedef unsigned int uint32;
typedef __attribute__((ext_vector_type(4))) uint32 uint4v;

#define MFMA16(a, b, c) __builtin_amdgcn_mfma_f32_16x16x32_f16((a), (b), (c), 0, 0, 0)

constexpr int B_ = 4, M_ = 1024, N_ = 4096, DQ_ = 512, DC_ = 512, H_ = 8, DH_ = 64, D_ = 512;
constexpr int KP_ = 576;       // K row stride (halves)
constexpr int VP_ = 4224;      // Vt row stride (halves)
constexpr int NSPLIT = 4;      // proven L2-coherent split
constexpr float QSC_ = 0.18033688011112042f;  // 0.125 * log2(e)

typedef __attribute__((address_space(1))) const void glds_g;
typedef __attribute__((address_space(3))) void glds_l;
__device__ __forceinline__ void g2lds16(const void* g, void* l) {
    __builtin_amdgcn_global_load_lds((glds_g*)g, (glds_l*)l, 16, 0, 0);
}

// ---- 64x64 f32->f16 transpose tile through LDS (device helper) ----
__device__ __forceinline__ void wtr_tile(const float* __restrict__ src, f16* __restrict__ dst,
                                         int Nout, int bx, int by, int tid) {
    __shared__ __align__(16) f16 Ts[64][72];
    const int n0 = bx * 64, k0 = by * 64;
    {
        int kr = tid >> 2, q4 = tid & 3;
        const float* sp = src + (size_t)(k0 + kr) * Nout + n0 + q4 * 16;
        float4 x0 = *(const float4*)(sp + 0), x1 = *(const float4*)(sp + 4);
        float4 x2 = *(const float4*)(sp + 8), x3 = *(const float4*)(sp + 12);
        half8 h0, h1;
        h0[0]=(f16)x0.x; h0[1]=(f16)x0.y; h0[2]=(f16)x0.z; h0[3]=(f16)x0.w;
        h0[4]=(f16)x1.x; h0[5]=(f16)x1.y; h0[6]=(f16)x1.z; h0[7]=(f16)x1.w;
        h1[0]=(f16)x2.x; h1[1]=(f16)x2.y; h1[2]=(f16)x2.z; h1[3]=(f16)x2.w;
        h1[4]=(f16)x3.x; h1[5]=(f16)x3.y; h1[6]=(f16)x3.z; h1[7]=(f16)x3.w;
        *(half8*)&Ts[kr][q4 * 16] = h0;
        *(half8*)&Ts[kr][q4 * 16 + 8] = h1;
    }
    __syncthreads();
    {
        int nr = tid >> 2, q = tid & 3;
        half8 h0, h1;
#pragma unroll
        for (int j = 0; j < 8; j++) { h0[j] = Ts[q * 16 + j][nr]; h1[j] = Ts[q * 16 + 8 + j][nr]; }
        f16* dp = dst + (size_t)(n0 + nr) * 512 + k0 + q * 16;
        *(half8*)(dp + 0) = h0;
        *(half8*)(dp + 8) = h1;
    }
}

// ---------------- prep: mask-pack + weight transposes only (casts fused into gemmqkv) --------
__global__ __launch_bounds__(256)
void prep_k(const void* __restrict__ mask, uint32* __restrict__ bits,
            const float* __restrict__ Wq, f16* __restrict__ wqt,
            const float* __restrict__ Wkv, f16* __restrict__ wkvt,
            const float* __restrict__ Wout, f16* __restrict__ woutt) {
    const int blk = blockIdx.x, tid = threadIdx.x;
    if (blk < 4096) {
        // dtype detect on the block's OWN 4KB word-window (in-bounds both layouts)
        __shared__ int s_bad;
        if (tid == 0) s_bad = 0;
        __syncthreads();
        const uint32* w = (const uint32*)mask + (size_t)blk * 1024;
        int bad = 0;
#pragma unroll
        for (int j = 0; j < 4; j++) bad |= (w[tid * 4 + j] & 0xFFFFFFFEu) != 0u;
        if (bad) s_bad = 1;  // benign race: all writers store 1
        __syncthreads();
        const bool bytes_mode = s_bad != 0;
        // thread owns elems [blk*4096 + tid*16, +16)
        uint32 v = 0;
        if (bytes_mode) {
            uint4 x = *(const uint4*)((const unsigned char*)mask + (size_t)blk * 4096 + tid * 16);
            uint32 ws_[4] = {x.x, x.y, x.z, x.w};
#pragma unroll
            for (int k = 0; k < 4; k++)
#pragma unroll
                for (int bb = 0; bb < 4; bb++)
                    v |= (((ws_[k] >> (8 * bb)) & 0xFFu) != 0u ? 1u : 0u) << (k * 4 + bb);
        } else {
            const uint4* p = (const uint4*)((const uint32*)mask + (size_t)blk * 4096 + tid * 16);
            uint4 x0 = p[0], x1 = p[1], x2 = p[2], x3 = p[3];
            uint32 ws_[16] = {x0.x, x0.y, x0.z, x0.w, x1.x, x1.y, x1.z, x1.w,
                              x2.x, x2.y, x2.z, x2.w, x3.x, x3.y, x3.z, x3.w};
#pragma unroll
            for (int k = 0; k < 16; k++) v |= (ws_[k] != 0u ? 1u : 0u) << k;
        }
        uint32 other = (uint32)__shfl_xor((int)v, 1);
        if ((tid & 1) == 0)
            bits[(size_t)blk * 128 + (tid >> 1)] = v | (other << 16);
    } else if (blk < 4160) {
        int r = blk - 4096;
        wtr_tile(Wq, wqt, 512, r & 7, r >> 3, tid);
    } else if (blk < 4288) {
        int r = blk - 4160;
        wtr_tile(Wkv, wkvt, 1024, r & 15, r >> 4, tid);
    } else {
        int r = blk - 4288;
        wtr_tile(Wout, woutt, 512, r & 7, r >> 3, tid);
    }
}

// ---------------- fused cast + q-proj + kv-proj GEMM (round-8 proven version) ----------------
// 128x128 tile, BK=64, 256 threads. f32 operand reg-staged (float4 -> cast -> ds_write),
// f16 weight side via g2lds16. Next K-step's f32 loads issued at compute start.
// XCD remap: XCD owns 8 m-panels x 8 n (2 m-groups): 2MB f32 A + 1MB B < 4MB L2.
__global__ __launch_bounds__(256)
void gemmqkv_k(const float* __restrict__ left, const f16* __restrict__ wqt,
               const float* __restrict__ right, const f16* __restrict__ wkvt,
               f16* __restrict__ qb, f16* __restrict__ kb, f16* __restrict__ vt) {
    __shared__ __align__(16) f16 As[128 * 64];
    __shared__ __align__(16) f16 Bs[128 * 64];
    const int hw = blockIdx.x, tid = threadIdx.x;
    const int lane = tid & 63, wave = tid >> 6;
    const int qd = lane >> 4, l16 = lane & 15;
    const int wm = wave >> 1, wn = wave & 1;

    // mode: 0 = K-half kv, 1 = V-half kv (swapped), 2 = q
    int mode;
    const float* F32b; const f16* F16b; size_t m0, n0;
    bool f32A;
    if (hw < 1024) {
        const int xcd = hw & 7, s = hw >> 3;               // s 0..127
        const int mi_ = (s >> 6) * 64 + xcd * 8 + (s & 7); // 0..127
        const int ni_ = (s >> 3) & 7;                      // 0..7
        size_t rows = (size_t)mi_ * 128, cols = (size_t)ni_ * 128;
        F32b = right + rows * 512;
        F16b = wkvt + cols * 512;
        if (cols < 512) { mode = 0; f32A = true;  m0 = rows; n0 = cols; }
        else            { mode = 1; f32A = false; m0 = cols; n0 = rows; }
    } else {
        const int r = hw - 1024;
        const int xcd = r & 7, s = r >> 3;                 // s 0..15
        const int mi_ = xcd * 4 + (s & 3);                 // 0..31
        const int ni_ = s >> 2;                            // 0..3
        mode = 2; f32A = true;
        m0 = (size_t)mi_ * 128; n0 = (size_t)ni_ * 128;
        F32b = left + m0 * 512;
        F16b = wqt + n0 * 512;
    }
    f16* LF32 = f32A ? As : Bs;   // LDS side receiving the f32-cast operand
    f16* LF16 = f32A ? Bs : As;

    // chunk geometry: chunk c = i*256 + tid -> row = c>>3, lds pos8 = c&7,
    // source col8 = (c&7) ^ (row&7)  (same swizzle both sides).
    int crow[4], ccol8[4];
    size_t g16off[4];
    f16* g16dst[4];
#pragma unroll
    for (int i = 0; i < 4; i++) {
        int c = i * 256 + wave * 64 + lane;
        int row = c >> 3, col8 = (c & 7) ^ (row & 7);
        crow[i] = row; ccol8[i] = col8;
        g16off[i] = (size_t)row * 512 + col8 * 8;
        g16dst[i] = LF16 + (size_t)(i * 256 + wave * 64) * 8;
    }

    floatx4 acc[4][4] = {};
    float4 ra[4][2];

    // prologue: f32 loads for k0 = 0
#pragma unroll
    for (int i = 0; i < 4; i++) {
        const float* sp = F32b + (size_t)crow[i] * 512 + ccol8[i] * 8;
        ra[i][0] = *(const float4*)sp;
        ra[i][1] = *(const float4*)(sp + 4);
    }

    for (int k0 = 0; k0 < 512; k0 += 64) {
        __syncthreads();   // ends prior compute's LDS reads (and drains in-flight vmem)
        // stage f16 side async + write f32-cast side from regs
#pragma unroll
        for (int i = 0; i < 4; i++) g2lds16(F16b + g16off[i] + k0, g16dst[i]);
#pragma unroll
        for (int i = 0; i < 4; i++) {
            half8 hh;
            hh[0] = (f16)ra[i][0].x; hh[1] = (f16)ra[i][0].y;
            hh[2] = (f16)ra[i][0].z; hh[3] = (f16)ra[i][0].w;
            hh[4] = (f16)ra[i][1].x; hh[5] = (f16)ra[i][1].y;
            hh[6] = (f16)ra[i][1].z; hh[7] = (f16)ra[i][1].w;
            *(half8*)&LF32[(size_t)(i * 256 + wave * 64 + lane) * 8] = hh;
        }
        __syncthreads();   // drains g2lds + ds_writes
        // issue next K-step's f32 loads now: latency hides under the MFMA phase
        if (k0 + 64 < 512) {
#pragma unroll
            for (int i = 0; i < 4; i++) {
                const float* sp = F32b + (size_t)crow[i] * 512 + (k0 + 64) + ccol8[i] * 8;
                ra[i][0] = *(const float4*)sp;
                ra[i][1] = *(const float4*)(sp + 4);
            }
        }
#pragma unroll
        for (int kk = 0; kk < 2; kk++) {
            half8 a[4], b[4];
#pragma unroll
            for (int t = 0; t < 4; t++) {
                int rowa = wm * 64 + t * 16 + l16;
                int rowb = wn * 64 + t * 16 + l16;
                int pa8 = ((kk * 4 + qd) ^ (rowa & 7)) * 8;
                int pb8 = ((kk * 4 + qd) ^ (rowb & 7)) * 8;
                a[t] = *(const half8*)&As[rowa * 64 + pa8];
                b[t] = *(const half8*)&Bs[rowb * 64 + pb8];
            }
#pragma unroll
            for (int mt = 0; mt < 4; mt++)
#pragma unroll
                for (int nt = 0; nt < 4; nt++)
                    acc[mt][nt] = MFMA16(a[mt], b[nt], acc[mt][nt]);
        }
    }

#pragma unroll
    for (int mt = 0; mt < 4; mt++)
#pragma unroll
        for (int nt = 0; nt < 4; nt++)
#pragma unroll
            for (int r = 0; r < 4; r++) {
                size_t mi = m0 + wm * 64 + mt * 16 + qd * 4 + r;  // C/D row index
                size_t ni = n0 + wn * 64 + nt * 16 + l16;         // C/D col index
                float v = acc[mt][nt][r];
                if (mode == 2) {
                    qb[mi * 512 + ni] = (f16)v;
                } else if (mode == 0) {
                    kb[mi * KP_ + ni] = (f16)v;
                } else {
                    int dcol = (int)mi - 512;
                    int hh = dcol >> 6, dh = dcol & 63;
                    size_t bb = ni >> 12, nn = ni & 4095;
                    vt[((bb * H_ + hh) * (size_t)DH_ + dh) * VP_ + nn] = (f16)v;
                }
            }
}

// ---------------- flash attention v8: v4 minus the K LDS round-trip ----------------
// Audit: ~41 of 66us was LDS-pipe occupancy; all 8 waves re-read the same K/V tiles.
// K per (b,h) is 512KB; bh-fastest grid => each XCD's K slice ~2MB < 4MB L2 -> L2-resident.
// v8 reads K fragments DIRECTLY from global (per s: two 64B sector-aligned reads/lane-group;
// qd lanes cover contiguous 64B) -> deletes K's g2lds and 8 of 16 ds_read_b128/iter.
// V stays in LDS (transposed layout). LDS 32->16KB. Everything else identical to v4.
__global__ __launch_bounds__(512, 8)
void attn_k(const f16* __restrict__ Qb, const f16* __restrict__ Kb,
            const f16* __restrict__ Vt, const uint32* __restrict__ mb,
            float* __restrict__ Op, float* __restrict__ Lp) {
    const int tid = threadIdx.x;
    const int lane = tid & 63, wave = tid >> 6;     // wave 0..7
    const int qd = lane >> 4, l16 = lane & 15;
    const int bh = blockIdx.x, b = bh >> 3, h = bh & 7;
    const int z = blockIdx.z;
    constexpr int iters = N_ / (64 * NSPLIT);   // 16
    const int n_base = z * iters * 64;
    const int m_base = blockIdx.y * 128 + wave * 16;

    __shared__ __align__(16) f16 Vs[2][64 * 64];   // [dh][n] chunks, xor-swizzled

    // Q B-operand fragments for this wave's 16 rows, pre-scaled by 0.125*log2(e)
    half8 q0, q1;
    {
        const f16* qrow = Qb + ((size_t)(b * M_ + m_base + l16)) * D_ + h * DH_;
        half8 r0 = *(const half8*)(qrow + qd * 8);
        half8 r1 = *(const half8*)(qrow + 32 + qd * 8);
#pragma unroll
        for (int j = 0; j < 8; j++) {
            q0[j] = (f16)((float)r0[j] * QSC_);
            q1[j] = (f16)((float)r1[j] * QSC_);
        }
    }

    floatx4 ot[4] = {};   // O^T: ot[sd][r] = O[m=l16][d = sd*16+qd*4+r]
    float l_acc = 0.0f;   // partial softmax denom for m=l16 over this lane's n subset

    // mask row for m = l16
    const uint32* mrow = mb + ((size_t)(b * M_ + m_base + l16)) * (N_ / 32);

    // V staging: wave w owns 8 rows [8w, 8w+8), 1 g2lds16 (pre-swizzled global source)
    const int srow = wave * 8;
    const int r8 = lane >> 3, p8 = lane & 7;
    const int gc8 = p8 ^ r8;
    const f16* vg = Vt + ((size_t)(bh * DH_) + srow + r8) * VP_ + gc8 * 8;

    auto stage = [&](int buf, int n0) {
        g2lds16(vg + n0, &Vs[buf][srow * 64]);
    };

    // K global row base: this lane reads row (b*N + n), bytes [h*128 + qd*16, +16) and +64
    const f16* krow = Kb + (size_t)(b * N_) * KP_ + h * DH_ + qd * 8;

    stage(0, n_base);
    uint2 mmc = *(const uint2*)(mrow + (n_base >> 5));
    int cur = 0;

    const int swz = (l16 & 7);   // read-side xor base (V)

    for (int it = 0; it < iters; it++) {
        const int n0 = n_base + it * 64;
        __syncthreads();
        uint2 mmn;
        if (it + 1 < iters) {
            stage(cur ^ 1, n0 + 64);
            mmn = *(const uint2*)(mrow + ((n0 + 64) >> 5));
        }

        const uint32 u0 = mmc.x >> (qd * 4);
        const uint32 u1 = mmc.y >> (qd * 4);

        // S^T = K·Q^T per 16-n subtile; K frags straight from L2-resident global
        uint32 pk[4][2];
#pragma unroll
        for (int s = 0; s < 4; s++) {
            const f16* kp = krow + (size_t)(n0 + s * 16 + l16) * KP_;
            half8 k0 = *(const half8*)kp;
            half8 k1 = *(const half8*)(kp + 32);
            floatx4 t = {};
            t = MFMA16(k0, q0, t);
            t = MFMA16(k1, q1, t);
            uint32 us = (s & 2 ? u1 : u0) >> ((s & 1) * 16);
            float e0 = __builtin_amdgcn_exp2f(t[0]);
            float e1 = __builtin_amdgcn_exp2f(t[1]);
            float e2 = __builtin_amdgcn_exp2f(t[2]);
            float e3 = __builtin_amdgcn_exp2f(t[3]);
            e0 = (us & 1u) ? e0 : 0.0f;
            e1 = (us & 2u) ? e1 : 0.0f;
            e2 = (us & 4u) ? e2 : 0.0f;
            e3 = (us & 8u) ? e3 : 0.0f;
            l_acc += (e0 + e1) + (e2 + e3);
            pk[s][0] = __builtin_bit_cast(uint32, __builtin_amdgcn_cvt_pkrtz(e0, e1));
            pk[s][1] = __builtin_bit_cast(uint32, __builtin_amdgcn_cvt_pkrtz(e2, e3));
        }

        // In-register routing: pa[hh] lane(qd,l16) elem j = P[m=l16][n=32hh+8qd+j]
        half8 pa[2];
#pragma unroll
        for (int hh = 0; hh < 2; hh++) {
            uint32 w0, w1, w2, w3;
            {
                auto a = __builtin_amdgcn_permlane32_swap(pk[2 * hh][0], pk[2 * hh + 1][0], false, false);
                auto c = __builtin_amdgcn_permlane16_swap(a[0], a[1], false, false);
                w0 = c[0]; w2 = c[1];
            }
            {
                auto a = __builtin_amdgcn_permlane32_swap(pk[2 * hh][1], pk[2 * hh + 1][1], false, false);
                auto c = __builtin_amdgcn_permlane16_swap(a[0], a[1], false, false);
                w1 = c[0]; w3 = c[1];
            }
            uint4v wv = {w0, w1, w2, w3};
            pa[hh] = __builtin_bit_cast(half8, wv);
        }

        // O^T += V^T @ P^T
#pragma unroll
        for (int sd = 0; sd < 4; sd++) {
            const int ro = (sd * 16 + l16) * 64;
            half8 v0 = *(const half8*)&Vs[cur][ro + ((qd ^ swz) * 8)];
            half8 v1 = *(const half8*)&Vs[cur][ro + (((4 + qd) ^ swz) * 8)];
            ot[sd] = MFMA16(v0, pa[0], ot[sd]);
            ot[sd] = MFMA16(v1, pa[1], ot[sd]);
        }
        mmc = mmn;
        cur ^= 1;
    }

    // reduce l over the 4 qd-lanes holding the same m (lane bits 4,5)
    l_acc += __shfl_xor(l_acc, 16);
    l_acc += __shfl_xor(l_acc, 32);

    // store f32 partials (non-temporal: don't evict K/V from L2)
    {
        size_t row = (size_t)(z * 32 + bh) * M_ + m_base + l16;
        float* op = Op + row * DH_ + qd * 4;
#pragma unroll
        for (int sd = 0; sd < 4; sd++)
            __builtin_nontemporal_store(ot[sd], (floatx4*)(op + sd * 16));
        if (qd == 0) __builtin_nontemporal_store(l_acc, Lp + row);
    }
}

// ---------------- combine splits: Ob = (sum Op) / (sum l), f16 (B*M, D), float4 ----------------
__global__ __launch_bounds__(256)
void comb_k(const float* __restrict__ Op, const float* __restrict__ Lp, f16* __restrict__ Ob,
            int nsp) {
    int i = blockIdx.x * 256 + threadIdx.x;   // B*M*D/4 = 524288 threads
    int d4 = i & 15, m = (i >> 4) & 1023, bh = i >> 14;
    float nx = 0.f, ny = 0.f, nz = 0.f, nw = 0.f, den = 0.f;
    for (int s = 0; s < nsp; s++) {
        size_t row = ((size_t)s * 32 + bh) * M_ + m;
        float4 x = *(const float4*)(Op + row * DH_ + d4 * 4);
        nx += x.x; ny += x.y; nz += x.z; nw += x.w;
        den += Lp[row];
    }
    float r = 1.0f / den;
    int b = bh >> 3, h = bh & 7;
    f16* o = Ob + ((size_t)(b * M_ + m)) * D_ + h * DH_ + d4 * 4;
    half4 hv; hv[0] = (f16)(nx * r); hv[1] = (f16)(ny * r); hv[2] = (f16)(nz * r); hv[3] = (f16)(nw * r);
    *(half4*)o = hv;
}

// ---------------- out-projection GEMM: 64x64 tiles, 2-phase double-buffered ----------------
__global__ __launch_bounds__(256)
void gemmout_k(const f16* __restrict__ A, const f16* __restrict__ Bt,
               float* __restrict__ Fout, const float* __restrict__ bias) {
    __shared__ __align__(16) f16 As[2][64 * 64];
    __shared__ __align__(16) f16 Bs[2][64 * 64];
    const int tid = threadIdx.x;
    const int lane = tid & 63, wave = tid >> 6;
    const int qd = lane >> 4, l16 = lane & 15;
    const int wm = wave >> 1, wn = wave & 1;
    const size_t m0 = (size_t)blockIdx.x * 64;
    const size_t n0 = (size_t)blockIdx.y * 64;

    size_t goff[2];
    f16 *la[2][2], *lb[2][2];
#pragma unroll
    for (int i = 0; i < 2; i++) {
        int c = i * 256 + wave * 64 + lane;
        int row = c >> 3, col8 = (c & 7) ^ (row & 7);
        goff[i] = (size_t)row * 512 + col8 * 8;
        la[0][i] = &As[0][(size_t)(i * 256 + wave * 64) * 8];
        la[1][i] = &As[1][(size_t)(i * 256 + wave * 64) * 8];
        lb[0][i] = &Bs[0][(size_t)(i * 256 + wave * 64) * 8];
        lb[1][i] = &Bs[1][(size_t)(i * 256 + wave * 64) * 8];
    }
    const f16* Ab = A + m0 * 512;
    const f16* Bb = Bt + n0 * 512;

    floatx4 acc[2][2] = {};

#pragma unroll
    for (int i = 0; i < 2; i++) g2lds16(Ab + goff[i], la[0][i]);
#pragma unroll
    for (int i = 0; i < 2; i++) g2lds16(Bb + goff[i], lb[0][i]);
    int cur = 0;

    for (int k0 = 0; k0 < 512; k0 += 64) {
        __syncthreads();
        if (k0 + 64 < 512) {
            const int nxt = cur ^ 1;
#pragma unroll
            for (int i = 0; i < 2; i++) g2lds16(Ab + goff[i] + k0 + 64, la[nxt][i]);
#pragma unroll
            for (int i = 0; i < 2; i++) g2lds16(Bb + goff[i] + k0 + 64, lb[nxt][i]);
        }
        const f16* Ac = &As[cur][0];
        const f16* Bc = &Bs[cur][0];
#pragma unroll
        for (int kk = 0; kk < 2; kk++) {
            half8 a[2], b[2];
#pragma unroll
            for (int t = 0; t < 2; t++) {
                int rowa = wm * 32 + t * 16 + l16;
                int rowb = wn * 32 + t * 16 + l16;
                int pa8 = ((kk * 4 + qd) ^ (rowa & 7)) * 8;
                int pb8 = ((kk * 4 + qd) ^ (rowb & 7)) * 8;
                a[t] = *(const half8*)&Ac[rowa * 64 + pa8];
                b[t] = *(const half8*)&Bc[rowb * 64 + pb8];
            }
#pragma unroll
            for (int mt = 0; mt < 2; mt++)
#pragma unroll
                for (int nt = 0; nt < 2; nt++)
                    acc[mt][nt] = MFMA16(a[mt], b[nt], acc[mt][nt]);
        }
        cur ^= 1;
    }

#pragma unroll
    for (int mt = 0; mt < 2; mt++)
#pragma unroll
        for (int nt = 0; nt < 2; nt++)
#pragma unroll
            for (int r = 0; r < 4; r++) {
                size_t row = m0 + wm * 32 + mt * 16 + qd * 4 + r;
                size_t col = n0 + wn * 32 + nt * 16 + l16;
                Fout[row * 512 + col] = acc[mt][nt][r] + bias[col];
            }
}

extern "C" void kernel_launch(void* const* d_in, const int* in_sizes, int n_in,
                              void* d_out, int out_size, void* d_ws, size_t ws_size,
                              hipStream_t stream) {
    const float* left  = (const float*)d_in[0];
    const float* right = (const float*)d_in[1];
    const void*  mask  = d_in[2];
    const float* Wq    = (const float*)d_in[3];
    const float* Wkv   = (const float*)d_in[4];
    const float* Wout  = (const float*)d_in[5];
    const float* bout  = (const float*)d_in[6];

    char* ws = (char*)d_ws;
    size_t off = 0;
    auto take = [&](size_t bytes) { char* p = ws + off; off += (bytes + 255) & ~(size_t)255; return p; };
    // ---- fixed allocations ----
    uint32* mbits = (uint32*)take((size_t)B_ * M_ * N_ / 8);           // 2 MB
    f16* woutt = (f16*)take((size_t)D_ * DQ_ * 2);                     // 0.5 MB
    f16* qb    = (f16*)take((size_t)B_ * M_ * D_ * 2);                 // 4 MB
    f16* kb    = (f16*)take((size_t)B_ * N_ * KP_ * 2);                // 18.9 MB (padded)
    f16* vt    = (f16*)take((size_t)B_ * H_ * DH_ * VP_ * 2);          // 17.3 MB (padded)
    f16* ob    = (f16*)take((size_t)B_ * M_ * D_ * 2);                 // 4 MB
    // ---- phase-overlay pool ----
    // phase 1 (prep+gemmqkv): wqt(0.5) wkvt(1)
    // phase 2 (attn+comb):    Op(32) + Lp(0.5) overlays the dead phase-1 buffers
    char* pool = (char*)take((size_t)34 * 1024 * 1024);
    f16* wqt    = (f16*)pool;
    f16* wkvt   = (f16*)(pool + (size_t)1 * 1024 * 1024);
    float* Op   = (float*)pool;                                        // 32 MB
    float* Lp   = (float*)(pool + (size_t)NSPLIT * 32 * M_ * DH_ * 4); // 0.5 MB

    // 5 dispatches total
    prep_k<<<4352, 256, 0, stream>>>(mask, mbits, Wq, wqt, Wkv, wkvt, Wout, woutt);
    gemmqkv_k<<<1152, 256, 0, stream>>>(left, wqt, right, wkvt, qb, kb, vt);
    attn_k<<<dim3(32, 8, NSPLIT), 512, 0, stream>>>(qb, kb, vt, mbits, Op, Lp);
    comb_k<<<2048, 256, 0, stream>>>(Op, Lp, ob, NSPLIT);
    gemmout_k<<<dim3(64, 8), 256, 0, stream>>>(ob, woutt, (float*)d_out, bout);
}

// Round 11
// 256.124 us; speedup vs baseline: 1.8524x; 1.3679x over previous
//
#include <hip/hip_runtime.h>

typedef _Float16 f16;
typedef __attribute__((ext_vector_type(8))) _Float16 half8;
typedef __attribute__((ext_vector_type(4))) _Float16 half4;
typedef __attribute__((ext_vector_type(4))) float floatx4;
typedef unsigned int uint32;
typedef __attribute__((ext_vector_type(4))) uint32 uint4v;

#define MFMA16(a, b, c) __builtin_amdgcn_mfma_f32_16x16x32_f16((a), (b), (c), 0, 0, 0)

constexpr int B_ = 4, M_ = 1024, N_ = 4096, DQ_ = 512, DC_ = 512, H_ = 8, DH_ = 64, D_ = 512;
constexpr int KP_ = 576;       // K row stride (halves)
constexpr int VP_ = 4224;      // Vt row stride (halves)
constexpr int NSPLIT = 4;      // proven L2-coherent split
constexpr float QSC_ = 0.18033688011112042f;  // 0.125 * log2(e)

typedef __attribute__((address_space(1))) const void glds_g;
typedef __attribute__((address_space(3))) void glds_l;
__device__ __forceinline__ void g2lds16(const void* g, void* l) {
    __builtin_amdgcn_global_load_lds((glds_g*)g, (glds_l*)l, 16, 0, 0);
}

// ---- 64x64 f32->f16 transpose tile through LDS (device helper) ----
__device__ __forceinline__ void wtr_tile(const float* __restrict__ src, f16* __restrict__ dst,
                                         int Nout, int bx, int by, int tid) {
    __shared__ __align__(16) f16 Ts[64][72];
    const int n0 = bx * 64, k0 = by * 64;
    {
        int kr = tid >> 2, q4 = tid & 3;
        const float* sp = src + (size_t)(k0 + kr) * Nout + n0 + q4 * 16;
        float4 x0 = *(const float4*)(sp + 0), x1 = *(const float4*)(sp + 4);
        float4 x2 = *(const float4*)(sp + 8), x3 = *(const float4*)(sp + 12);
        half8 h0, h1;
        h0[0]=(f16)x0.x; h0[1]=(f16)x0.y; h0[2]=(f16)x0.z; h0[3]=(f16)x0.w;
        h0[4]=(f16)x1.x; h0[5]=(f16)x1.y; h0[6]=(f16)x1.z; h0[7]=(f16)x1.w;
        h1[0]=(f16)x2.x; h1[1]=(f16)x2.y; h1[2]=(f16)x2.z; h1[3]=(f16)x2.w;
        h1[4]=(f16)x3.x; h1[5]=(f16)x3.y; h1[6]=(f16)x3.z; h1[7]=(f16)x3.w;
        *(half8*)&Ts[kr][q4 * 16] = h0;
        *(half8*)&Ts[kr][q4 * 16 + 8] = h1;
    }
    __syncthreads();
    {
        int nr = tid >> 2, q = tid & 3;
        half8 h0, h1;
#pragma unroll
        for (int j = 0; j < 8; j++) { h0[j] = Ts[q * 16 + j][nr]; h1[j] = Ts[q * 16 + 8 + j][nr]; }
        f16* dp = dst + (size_t)(n0 + nr) * 512 + k0 + q * 16;
        *(half8*)(dp + 0) = h0;
        *(half8*)(dp + 8) = h1;
    }
}

// ---------------- prep: weight transposes only (mask-pack merged into gemmqkv) --------------
// regions: [0,64) wtr Wq | [64,192) wtr Wkv | [192,256) wtr Wout
__global__ __launch_bounds__(256)
void prep_k(const float* __restrict__ Wq, f16* __restrict__ wqt,
            const float* __restrict__ Wkv, f16* __restrict__ wkvt,
            const float* __restrict__ Wout, f16* __restrict__ woutt) {
    const int blk = blockIdx.x, tid = threadIdx.x;
    if (blk < 64) {
        wtr_tile(Wq, wqt, 512, blk & 7, blk >> 3, tid);
    } else if (blk < 192) {
        int r = blk - 64;
        wtr_tile(Wkv, wkvt, 1024, r & 15, r >> 4, tid);
    } else {
        int r = blk - 192;
        wtr_tile(Wout, woutt, 512, r & 7, r >> 3, tid);
    }
}

// ---------------- fused cast + q/kv-proj GEMM + mask-pack rider blocks ----------------------
// blocks [0,1152): round-8 proven GEMM (128x128, BK=64, f32 reg-staged + f16 g2lds,
//   XCD remap). blocks [1152,5248): mask-pack (memory-bound) rides along, filling CU
//   bubbles -- its output (mbits) is first consumed by attn_k, one dispatch later, so
//   the former prep mask time + one launch gap collapse into this kernel's shadow.
__global__ __launch_bounds__(256)
void gemmqkv_k(const float* __restrict__ left, const f16* __restrict__ wqt,
               const float* __restrict__ right, const f16* __restrict__ wkvt,
               f16* __restrict__ qb, f16* __restrict__ kb, f16* __restrict__ vt,
               const void* __restrict__ mask, uint32* __restrict__ bits) {
    const int hw = blockIdx.x, tid = threadIdx.x;

    if (hw >= 1152) {
        // ---- mask-pack rider: single-round 16-elem/thread (uint4 loads + shfl merge) ----
        const int blk = hw - 1152;
        __shared__ int s_bad;
        if (tid == 0) s_bad = 0;
        __syncthreads();
        const uint32* w = (const uint32*)mask + (size_t)blk * 1024;
        int bad = 0;
#pragma unroll
        for (int j = 0; j < 4; j++) bad |= (w[tid * 4 + j] & 0xFFFFFFFEu) != 0u;
        if (bad) s_bad = 1;  // benign race: all writers store 1
        __syncthreads();
        const bool bytes_mode = s_bad != 0;
        uint32 v = 0;
        if (bytes_mode) {
            uint4 x = *(const uint4*)((const unsigned char*)mask + (size_t)blk * 4096 + tid * 16);
            uint32 ws_[4] = {x.x, x.y, x.z, x.w};
#pragma unroll
            for (int k = 0; k < 4; k++)
#pragma unroll
                for (int bb = 0; bb < 4; bb++)
                    v |= (((ws_[k] >> (8 * bb)) & 0xFFu) != 0u ? 1u : 0u) << (k * 4 + bb);
        } else {
            const uint4* p = (const uint4*)((const uint32*)mask + (size_t)blk * 4096 + tid * 16);
            uint4 x0 = p[0], x1 = p[1], x2 = p[2], x3 = p[3];
            uint32 ws_[16] = {x0.x, x0.y, x0.z, x0.w, x1.x, x1.y, x1.z, x1.w,
                              x2.x, x2.y, x2.z, x2.w, x3.x, x3.y, x3.z, x3.w};
#pragma unroll
            for (int k = 0; k < 16; k++) v |= (ws_[k] != 0u ? 1u : 0u) << k;
        }
        uint32 other = (uint32)__shfl_xor((int)v, 1);
        if ((tid & 1) == 0)
            bits[(size_t)blk * 128 + (tid >> 1)] = v | (other << 16);
        return;
    }

    // ---- GEMM blocks (round-8 proven body) ----
    __shared__ __align__(16) f16 As[128 * 64];
    __shared__ __align__(16) f16 Bs[128 * 64];
    const int lane = tid & 63, wave = tid >> 6;
    const int qd = lane >> 4, l16 = lane & 15;
    const int wm = wave >> 1, wn = wave & 1;

    // mode: 0 = K-half kv, 1 = V-half kv (swapped), 2 = q
    int mode;
    const float* F32b; const f16* F16b; size_t m0, n0;
    bool f32A;
    if (hw < 1024) {
        const int xcd = hw & 7, s = hw >> 3;               // s 0..127
        const int mi_ = (s >> 6) * 64 + xcd * 8 + (s & 7); // 0..127
        const int ni_ = (s >> 3) & 7;                      // 0..7
        size_t rows = (size_t)mi_ * 128, cols = (size_t)ni_ * 128;
        F32b = right + rows * 512;
        F16b = wkvt + cols * 512;
        if (cols < 512) { mode = 0; f32A = true;  m0 = rows; n0 = cols; }
        else            { mode = 1; f32A = false; m0 = cols; n0 = rows; }
    } else {
        const int r = hw - 1024;
        const int xcd = r & 7, s = r >> 3;                 // s 0..15
        const int mi_ = xcd * 4 + (s & 3);                 // 0..31
        const int ni_ = s >> 2;                            // 0..3
        mode = 2; f32A = true;
        m0 = (size_t)mi_ * 128; n0 = (size_t)ni_ * 128;
        F32b = left + m0 * 512;
        F16b = wqt + n0 * 512;
    }
    f16* LF32 = f32A ? As : Bs;   // LDS side receiving the f32-cast operand
    f16* LF16 = f32A ? Bs : As;

    int crow[4], ccol8[4];
    size_t g16off[4];
    f16* g16dst[4];
#pragma unroll
    for (int i = 0; i < 4; i++) {
        int c = i * 256 + wave * 64 + lane;
        int row = c >> 3, col8 = (c & 7) ^ (row & 7);
        crow[i] = row; ccol8[i] = col8;
        g16off[i] = (size_t)row * 512 + col8 * 8;
        g16dst[i] = LF16 + (size_t)(i * 256 + wave * 64) * 8;
    }

    floatx4 acc[4][4] = {};
    float4 ra[4][2];

    // prologue: f32 loads for k0 = 0
#pragma unroll
    for (int i = 0; i < 4; i++) {
        const float* sp = F32b + (size_t)crow[i] * 512 + ccol8[i] * 8;
        ra[i][0] = *(const float4*)sp;
        ra[i][1] = *(const float4*)(sp + 4);
    }

    for (int k0 = 0; k0 < 512; k0 += 64) {
        __syncthreads();   // ends prior compute's LDS reads (and drains in-flight vmem)
#pragma unroll
        for (int i = 0; i < 4; i++) g2lds16(F16b + g16off[i] + k0, g16dst[i]);
#pragma unroll
        for (int i = 0; i < 4; i++) {
            half8 hh;
            hh[0] = (f16)ra[i][0].x; hh[1] = (f16)ra[i][0].y;
            hh[2] = (f16)ra[i][0].z; hh[3] = (f16)ra[i][0].w;
            hh[4] = (f16)ra[i][1].x; hh[5] = (f16)ra[i][1].y;
            hh[6] = (f16)ra[i][1].z; hh[7] = (f16)ra[i][1].w;
            *(half8*)&LF32[(size_t)(i * 256 + wave * 64 + lane) * 8] = hh;
        }
        __syncthreads();   // drains g2lds + ds_writes
        if (k0 + 64 < 512) {
#pragma unroll
            for (int i = 0; i < 4; i++) {
                const float* sp = F32b + (size_t)crow[i] * 512 + (k0 + 64) + ccol8[i] * 8;
                ra[i][0] = *(const float4*)sp;
                ra[i][1] = *(const float4*)(sp + 4);
            }
        }
#pragma unroll
        for (int kk = 0; kk < 2; kk++) {
            half8 a[4], b[4];
#pragma unroll
            for (int t = 0; t < 4; t++) {
                int rowa = wm * 64 + t * 16 + l16;
                int rowb = wn * 64 + t * 16 + l16;
                int pa8 = ((kk * 4 + qd) ^ (rowa & 7)) * 8;
                int pb8 = ((kk * 4 + qd) ^ (rowb & 7)) * 8;
                a[t] = *(const half8*)&As[rowa * 64 + pa8];
                b[t] = *(const half8*)&Bs[rowb * 64 + pb8];
            }
#pragma unroll
            for (int mt = 0; mt < 4; mt++)
#pragma unroll
                for (int nt = 0; nt < 4; nt++)
                    acc[mt][nt] = MFMA16(a[mt], b[nt], acc[mt][nt]);
        }
    }

#pragma unroll
    for (int mt = 0; mt < 4; mt++)
#pragma unroll
        for (int nt = 0; nt < 4; nt++)
#pragma unroll
            for (int r = 0; r < 4; r++) {
                size_t mi = m0 + wm * 64 + mt * 16 + qd * 4 + r;  // C/D row index
                size_t ni = n0 + wn * 64 + nt * 16 + l16;         // C/D col index
                float v = acc[mt][nt][r];
                if (mode == 2) {
                    qb[mi * 512 + ni] = (f16)v;
                } else if (mode == 0) {
                    kb[mi * KP_ + ni] = (f16)v;
                } else {
                    int dcol = (int)mi - 512;
                    int hh = dcol >> 6, dh = dcol & 63;
                    size_t bb = ni >> 12, nn = ni & 4095;
                    vt[((bb * H_ + hh) * (size_t)DH_ + dh) * VP_ + nn] = (f16)v;
                }
            }
}

// ---------------- flash attention v4 (quadruple-confirmed optimum, 66.5us) -------------------
// Thin waves (16 rows) + max TLP. K AND V both LDS-staged, double-buffered (v8 lesson:
// K-from-global exposes L2 latency on the QK chain, 154us; the LDS round-trip is a
// latency-decoupling buffer, not redundancy).
__global__ __launch_bounds__(512, 8)
void attn_k(const f16* __restrict__ Qb, const f16* __restrict__ Kb,
            const f16* __restrict__ Vt, const uint32* __restrict__ mb,
            float* __restrict__ Op, float* __restrict__ Lp) {
    const int tid = threadIdx.x;
    const int lane = tid & 63, wave = tid >> 6;     // wave 0..7
    const int qd = lane >> 4, l16 = lane & 15;
    const int bh = blockIdx.x, b = bh >> 3, h = bh & 7;
    const int z = blockIdx.z;
    constexpr int iters = N_ / (64 * NSPLIT);   // 16
    const int n_base = z * iters * 64;
    const int m_base = blockIdx.y * 128 + wave * 16;

    __shared__ __align__(16) f16 Ks[2][64 * 64];   // [n][d] chunks, xor-swizzled
    __shared__ __align__(16) f16 Vs[2][64 * 64];   // [dh][n] chunks, xor-swizzled

    // Q B-operand fragments for this wave's 16 rows, pre-scaled by 0.125*log2(e)
    half8 q0, q1;
    {
        const f16* qrow = Qb + ((size_t)(b * M_ + m_base + l16)) * D_ + h * DH_;
        half8 r0 = *(const half8*)(qrow + qd * 8);
        half8 r1 = *(const half8*)(qrow + 32 + qd * 8);
#pragma unroll
        for (int j = 0; j < 8; j++) {
            q0[j] = (f16)((float)r0[j] * QSC_);
            q1[j] = (f16)((float)r1[j] * QSC_);
        }
    }

    floatx4 ot[4] = {};   // O^T: ot[sd][r] = O[m=l16][d = sd*16+qd*4+r]
    float l_acc = 0.0f;   // partial softmax denom for m=l16 over this lane's n subset

    // mask row for m = l16
    const uint32* mrow = mb + ((size_t)(b * M_ + m_base + l16)) * (N_ / 32);

    // staging: wave w owns 8 rows [8w, 8w+8) of each tile, 1 g2lds16 each for K and V.
    const int srow = wave * 8;
    const int r8 = lane >> 3, p8 = lane & 7;
    const int gc8 = p8 ^ r8;
    const f16* kg = Kb + ((size_t)(b * N_) + srow + r8) * KP_ + h * DH_ + gc8 * 8;
    const f16* vg = Vt + ((size_t)(bh * DH_) + srow + r8) * VP_ + gc8 * 8;

    auto stage = [&](int buf, int n0) {
        g2lds16(kg + (size_t)n0 * KP_, &Ks[buf][srow * 64]);
        g2lds16(vg + n0, &Vs[buf][srow * 64]);
    };

    stage(0, n_base);
    uint2 mmc = *(const uint2*)(mrow + (n_base >> 5));
    int cur = 0;

    const int swz = (l16 & 7);   // read-side xor base

    for (int it = 0; it < iters; it++) {
        const int n0 = n_base + it * 64;
        __syncthreads();
        uint2 mmn;
        if (it + 1 < iters) {
            stage(cur ^ 1, n0 + 64);
            mmn = *(const uint2*)(mrow + ((n0 + 64) >> 5));
        }

        const uint32 u0 = mmc.x >> (qd * 4);
        const uint32 u1 = mmc.y >> (qd * 4);

        // S^T = K·Q^T per 16-n subtile; mask; P = exp2; accumulate l; pack pairs (RTZ)
        uint32 pk[4][2];
#pragma unroll
        for (int s = 0; s < 4; s++) {
            const int ro = (s * 16 + l16) * 64;
            half8 k0 = *(const half8*)&Ks[cur][ro + ((qd ^ swz) * 8)];
            half8 k1 = *(const half8*)&Ks[cur][ro + (((4 + qd) ^ swz) * 8)];
            floatx4 t = {};
            t = MFMA16(k0, q0, t);
            t = MFMA16(k1, q1, t);
            uint32 us = (s & 2 ? u1 : u0) >> ((s & 1) * 16);
            float e0 = __builtin_amdgcn_exp2f(t[0]);
            float e1 = __builtin_amdgcn_exp2f(t[1]);
            float e2 = __builtin_amdgcn_exp2f(t[2]);
            float e3 = __builtin_amdgcn_exp2f(t[3]);
            e0 = (us & 1u) ? e0 : 0.0f;
            e1 = (us & 2u) ? e1 : 0.0f;
            e2 = (us & 4u) ? e2 : 0.0f;
            e3 = (us & 8u) ? e3 : 0.0f;
            l_acc += (e0 + e1) + (e2 + e3);
            pk[s][0] = __builtin_bit_cast(uint32, __builtin_amdgcn_cvt_pkrtz(e0, e1));
            pk[s][1] = __builtin_bit_cast(uint32, __builtin_amdgcn_cvt_pkrtz(e2, e3));
        }

        // In-register routing: pa[hh] lane(qd,l16) elem j = P[m=l16][n=32hh+8qd+j]
        half8 pa[2];
#pragma unroll
        for (int hh = 0; hh < 2; hh++) {
            uint32 w0, w1, w2, w3;
            {
                auto a = __builtin_amdgcn_permlane32_swap(pk[2 * hh][0], pk[2 * hh + 1][0], false, false);
                auto c = __builtin_amdgcn_permlane16_swap(a[0], a[1], false, false);
                w0 = c[0]; w2 = c[1];
            }
            {
                auto a = __builtin_amdgcn_permlane32_swap(pk[2 * hh][1], pk[2 * hh + 1][1], false, false);
                auto c = __builtin_amdgcn_permlane16_swap(a[0], a[1], false, false);
                w1 = c[0]; w3 = c[1];
            }
            uint4v wv = {w0, w1, w2, w3};
            pa[hh] = __builtin_bit_cast(half8, wv);
        }

        // O^T += V^T @ P^T
#pragma unroll
        for (int sd = 0; sd < 4; sd++) {
            const int ro = (sd * 16 + l16) * 64;
            half8 v0 = *(const half8*)&Vs[cur][ro + ((qd ^ swz) * 8)];
            half8 v1 = *(const half8*)&Vs[cur][ro + (((4 + qd) ^ swz) * 8)];
            ot[sd] = MFMA16(v0, pa[0], ot[sd]);
            ot[sd] = MFMA16(v1, pa[1], ot[sd]);
        }
        mmc = mmn;
        cur ^= 1;
    }

    // reduce l over the 4 qd-lanes holding the same m (lane bits 4,5)
    l_acc += __shfl_xor(l_acc, 16);
    l_acc += __shfl_xor(l_acc, 32);

    // store f32 partials (non-temporal: don't evict K/V from L2)
    {
        size_t row = (size_t)(z * 32 + bh) * M_ + m_base + l16;
        float* op = Op + row * DH_ + qd * 4;
#pragma unroll
        for (int sd = 0; sd < 4; sd++)
            __builtin_nontemporal_store(ot[sd], (floatx4*)(op + sd * 16));
        if (qd == 0) __builtin_nontemporal_store(l_acc, Lp + row);
    }
}

// ---------------- combine splits: Ob = (sum Op) / (sum l), f16 (B*M, D), float4 ----------------
__global__ __launch_bounds__(256)
void comb_k(const float* __restrict__ Op, const float* __restrict__ Lp, f16* __restrict__ Ob,
            int nsp) {
    int i = blockIdx.x * 256 + threadIdx.x;   // B*M*D/4 = 524288 threads
    int d4 = i & 15, m = (i >> 4) & 1023, bh = i >> 14;
    float nx = 0.f, ny = 0.f, nz = 0.f, nw = 0.f, den = 0.f;
    for (int s = 0; s < nsp; s++) {
        size_t row = ((size_t)s * 32 + bh) * M_ + m;
        float4 x = *(const float4*)(Op + row * DH_ + d4 * 4);
        nx += x.x; ny += x.y; nz += x.z; nw += x.w;
        den += Lp[row];
    }
    float r = 1.0f / den;
    int b = bh >> 3, h = bh & 7;
    f16* o = Ob + ((size_t)(b * M_ + m)) * D_ + h * DH_ + d4 * 4;
    half4 hv; hv[0] = (f16)(nx * r); hv[1] = (f16)(ny * r); hv[2] = (f16)(nz * r); hv[3] = (f16)(nw * r);
    *(half4*)o = hv;
}

// ---------------- out-projection GEMM: 64x64 tiles, 2-phase double-buffered ----------------
__global__ __launch_bounds__(256)
void gemmout_k(const f16* __restrict__ A, const f16* __restrict__ Bt,
               float* __restrict__ Fout, const float* __restrict__ bias) {
    __shared__ __align__(16) f16 As[2][64 * 64];
    __shared__ __align__(16) f16 Bs[2][64 * 64];
    const int tid = threadIdx.x;
    const int lane = tid & 63, wave = tid >> 6;
    const int qd = lane >> 4, l16 = lane & 15;
    const int wm = wave >> 1, wn = wave & 1;
    const size_t m0 = (size_t)blockIdx.x * 64;
    const size_t n0 = (size_t)blockIdx.y * 64;

    size_t goff[2];
    f16 *la[2][2], *lb[2][2];
#pragma unroll
    for (int i = 0; i < 2; i++) {
        int c = i * 256 + wave * 64 + lane;
        int row = c >> 3, col8 = (c & 7) ^ (row & 7);
        goff[i] = (size_t)row * 512 + col8 * 8;
        la[0][i] = &As[0][(size_t)(i * 256 + wave * 64) * 8];
        la[1][i] = &As[1][(size_t)(i * 256 + wave * 64) * 8];
        lb[0][i] = &Bs[0][(size_t)(i * 256 + wave * 64) * 8];
        lb[1][i] = &Bs[1][(size_t)(i * 256 + wave * 64) * 8];
    }
    const f16* Ab = A + m0 * 512;
    const f16* Bb = Bt + n0 * 512;

    floatx4 acc[2][2] = {};

#pragma unroll
    for (int i = 0; i < 2; i++) g2lds16(Ab + goff[i], la[0][i]);
#pragma unroll
    for (int i = 0; i < 2; i++) g2lds16(Bb + goff[i], lb[0][i]);
    int cur = 0;

    for (int k0 = 0; k0 < 512; k0 += 64) {
        __syncthreads();
        if (k0 + 64 < 512) {
            const int nxt = cur ^ 1;
#pragma unroll
            for (int i = 0; i < 2; i++) g2lds16(Ab + goff[i] + k0 + 64, la[nxt][i]);
#pragma unroll
            for (int i = 0; i < 2; i++) g2lds16(Bb + goff[i] + k0 + 64, lb[nxt][i]);
        }
        const f16* Ac = &As[cur][0];
        const f16* Bc = &Bs[cur][0];
#pragma unroll
        for (int kk = 0; kk < 2; kk++) {
            half8 a[2], b[2];
#pragma unroll
            for (int t = 0; t < 2; t++) {
                int rowa = wm * 32 + t * 16 + l16;
                int rowb = wn * 32 + t * 16 + l16;
                int pa8 = ((kk * 4 + qd) ^ (rowa & 7)) * 8;
                int pb8 = ((kk * 4 + qd) ^ (rowb & 7)) * 8;
                a[t] = *(const half8*)&Ac[rowa * 64 + pa8];
                b[t] = *(const half8*)&Bc[rowb * 64 + pb8];
            }
#pragma unroll
            for (int mt = 0; mt < 2; mt++)
#pragma unroll
                for (int nt = 0; nt < 2; nt++)
                    acc[mt][nt] = MFMA16(a[mt], b[nt], acc[mt][nt]);
        }
        cur ^= 1;
    }

#pragma unroll
    for (int mt = 0; mt < 2; mt++)
#pragma unroll
        for (int nt = 0; nt < 2; nt++)
#pragma unroll
            for (int r = 0; r < 4; r++) {
                size_t row = m0 + wm * 32 + mt * 16 + qd * 4 + r;
                size_t col = n0 + wn * 32 + nt * 16 + l16;
                Fout[row * 512 + col] = acc[mt][nt][r] + bias[col];
            }
}

extern "C" void kernel_launch(void* const* d_in, const int* in_sizes, int n_in,
                              void* d_out, int out_size, void* d_ws, size_t ws_size,
                              hipStream_t stream) {
    const float* left  = (const float*)d_in[0];
    const float* right = (const float*)d_in[1];
    const void*  mask  = d_in[2];
    const float* Wq    = (const float*)d_in[3];
    const float* Wkv   = (const float*)d_in[4];
    const float* Wout  = (const float*)d_in[5];
    const float* bout  = (const float*)d_in[6];

    char* ws = (char*)d_ws;
    size_t off = 0;
    auto take = [&](size_t bytes) { char* p = ws + off; off += (bytes + 255) & ~(size_t)255; return p; };
    // ---- fixed allocations ----
    uint32* mbits = (uint32*)take((size_t)B_ * M_ * N_ / 8);           // 2 MB
    f16* woutt = (f16*)take((size_t)D_ * DQ_ * 2);                     // 0.5 MB
    f16* qb    = (f16*)take((size_t)B_ * M_ * D_ * 2);                 // 4 MB
    f16* kb    = (f16*)take((size_t)B_ * N_ * KP_ * 2);                // 18.9 MB (padded)
    f16* vt    = (f16*)take((size_t)B_ * H_ * DH_ * VP_ * 2);          // 17.3 MB (padded)
    f16* ob    = (f16*)take((size_t)B_ * M_ * D_ * 2);                 // 4 MB
    // ---- phase-overlay pool ----
    // phase 1 (prep+gemmqkv): wqt(0.5) wkvt(1)
    // phase 2 (attn+comb):    Op(32) + Lp(0.5) overlays the dead phase-1 buffers
    char* pool = (char*)take((size_t)34 * 1024 * 1024);
    f16* wqt    = (f16*)pool;
    f16* wkvt   = (f16*)(pool + (size_t)1 * 1024 * 1024);
    float* Op   = (float*)pool;                                        // 32 MB
    float* Lp   = (float*)(pool + (size_t)NSPLIT * 32 * M_ * DH_ * 4); // 0.5 MB

    // 5 dispatches total
    prep_k<<<256, 256, 0, stream>>>(Wq, wqt, Wkv, wkvt, Wout, woutt);
    gemmqkv_k<<<5248, 256, 0, stream>>>(left, wqt, right, wkvt, qb, kb, vt, mask, mbits);
    attn_k<<<dim3(32, 8, NSPLIT), 512, 0, stream>>>(qb, kb, vt, mbits, Op, Lp);
    comb_k<<<2048, 256, 0, stream>>>(Op, Lp, ob, NSPLIT);
    gemmout_k<<<dim3(64, 8), 256, 0, stream>>>(ob, woutt, (float*)d_out, bout);
}